// Round 12
// baseline (61.028 us; speedup 1.0000x reference)
//
#include <hip/hip_runtime.h>
#include <math.h>

#define SEQ   3000
#define FDIM  64
// 999 steps = 111 groups (g0..g110) x 9 steps. Channel-parallel quads (R9):
// lane p computes channel p of one (b,f) chain; lane3 mirrors ch2.
// R12: 9-hop dependence chain (balanced rcp/exp paths converge in final fma)
// + QUAD-buffered asm loads with vmcnt(27) boundary waits -> every wait only
// needs VMEM >= 2 phases (~2600 cy) old; stores younger than 2 phases are
// never waited on. Hand-scheduled asm step body (R11), SGPR bases.

#define PPWc  0.23164189f                  // 0.3275911 / sqrt(2)
#define B1f   0.127414796f                 // 0.5*0.254829592
#define B2f   (-0.142248368f)              // 0.5*-0.284496736
#define B3f   0.7107068705f                // 0.5*1.421413741
#define B4f   (-0.7265760135f)             // 0.5*-1.453152027
#define B5f   0.5307027145f                // 0.5*1.061405429
#define NL2Ef (-0.72134752044448170368f)   // -0.5*log2(e)

#define DECL9(p) float p##0,p##1,p##2,p##3,p##4,p##5,p##6,p##7,p##8
#define TOUCH9(P) "+v"(P##0),"+v"(P##1),"+v"(P##2),"+v"(P##3),"+v"(P##4),     \
    "+v"(P##5),"+v"(P##6),"+v"(P##7),"+v"(P##8)

// prefetch 1 value via SGPR base + per-lane constant voffset
#define PF1S(dst, OFF) asm volatile(                                          \
    "global_load_dword %0, %1, %2 offset:" #OFF                               \
    : "=v"(dst) : "v"(voff), "s"(lbase) : "memory")

#define WAITVM(Nlit, P) do {                                                  \
    asm volatile("s_waitcnt vmcnt(" #Nlit ")" : TOUCH9(P) : : "memory");      \
    __builtin_amdgcn_sched_barrier(0);                                        \
} while (0)

// --- chain head: matvec + both trans launches (hand-spaced fillers) ---
// chain: s -> {dpp,f1}@1 -> fmac@2 -> a@3 -> {u2,dd,rl}@4 -> {m,rcp,rlu-}@5
#define ASMA() asm volatile(                                                  \
    "v_fma_f32 %[a], %[wa], %[s], %[q]\n\t"                                   \
    "v_mov_b32_dpp %[d1], %[s] quad_perm:[1,2,0,0] row_mask:0xf bank_mask:0xf\n\t" \
    "v_mov_b32_dpp %[d2], %[s] quad_perm:[2,0,1,1] row_mask:0xf bank_mask:0xf\n\t" \
    "v_fmac_f32 %[a], %[wb], %[d1]\n\t"                                       \
    "v_fmac_f32 %[a], %[wc], %[d2]\n\t"                                       \
    "v_mul_f32 %[u2], %[a], %[a]\n\t"                                         \
    "v_max_f32 %[rl], 0, %[a]\n\t"                                            \
    "v_fma_f32 %[dd], %[ppw], abs(%[a]), 1.0\n\t"                             \
    "v_mul_f32 %[m], %[u2], %[nl2e]\n\t"                                      \
    "v_rcp_f32 %[r], %[dd]\n\t"                                               \
    "v_exp_f32 %[e], %[m]"                                                    \
    : [a]"=&v"(a_), [d1]"=&v"(d1_), [d2]"=&v"(d2_), [u2]"=&v"(u2_),           \
      [dd]"=&v"(dd_), [m]"=&v"(m_), [r]"=&v"(r_), [e]"=&v"(e_), [rl]"=&v"(rl_)\
    : [s]"v"(s), [wa]"v"(wA), [wb]"v"(wB), [wc]"v"(wC), [q]"v"(q),            \
      [ppw]"v"(cPPW), [nl2e]"v"(cNL2E))

// --- 9-hop tail: rcp-path (c01,c23,rr -> pp -> pp2 @8) and exp-path
// (z@7 -> zr@8) converge in the final fma @9. Store spaces s-write from
// next step's dpp read.
#define ASMB(U, OFF) asm volatile(                                            \
    "v_fma_f32 %[c01], %[b2], %[r], %[b1]\n\t"                                \
    "v_fma_f32 %[c23], %[b4], %[r], %[b3]\n\t"                                \
    "v_mul_f32 %[rr], %[r], %[r]\n\t"                                         \
    "v_mul_f32 %[z], -abs(%[a]), %[e]\n\t"                                    \
    "v_add_f32 %[rlu], %[rl], %[u]\n\t"                                       \
    "v_fma_f32 %[pp], %[c23], %[rr], %[c01]\n\t"                              \
    "v_mul_f32 %[r4], %[rr], %[rr]\n\t"                                       \
    "v_mul_f32 %[zr], %[z], %[r]\n\t"                                         \
    "v_fmac_f32 %[pp], %[b5], %[r4]\n\t"                                      \
    "v_fma_f32 %[s], %[pp], %[zr], %[rlu]\n\t"                                \
    "global_store_dword %[vo], %[s], %[ob] offset:" #OFF                      \
    : [s]"=&v"(s), [c01]"=&v"(c01_), [c23]"=&v"(c23_), [rr]"=&v"(rr_),        \
      [r4]"=&v"(r4_), [pp]"=&v"(pp_), [zr]"=&v"(zr_), [z]"=&v"(z_),           \
      [rlu]"=&v"(rlu_)                                                        \
    : [a]"v"(a_), [r]"v"(r_), [e]"v"(e_), [rl]"v"(rl_), [u]"v"(U),            \
      [b1]"v"(cB1), [b2]"v"(cB2), [b3]"v"(cB3), [b4]"v"(cB4), [b5]"v"(cB5),   \
      [vo]"v"(voff), [ob]"s"(obase)                                           \
    : "memory")

#define STEP_LD(U, LD, OFF)  do { ASMA(); PF1S(LD, OFF); ASMB(U, OFF); } while (0)
#define STEP_NOLD(U, OFF)    do { ASMA(); ASMB(U, OFF); } while (0)

// one group = 9 steps; loads target buffer L (group g+3); bases bump 2304 B
// (576 floats) every 3 steps so all offset immediates stay in {0,768,1536}.
#define GRP_LD(P, L) do {                                                     \
    STEP_LD(P##0, L##0, 0); STEP_LD(P##1, L##1, 768); STEP_LD(P##2, L##2, 1536);\
    lbase += 576; obase += 576;                                               \
    STEP_LD(P##3, L##3, 0); STEP_LD(P##4, L##4, 768); STEP_LD(P##5, L##5, 1536);\
    lbase += 576; obase += 576;                                               \
    STEP_LD(P##6, L##6, 0); STEP_LD(P##7, L##7, 768); STEP_LD(P##8, L##8, 1536);\
    lbase += 576; obase += 576;                                               \
} while (0)

#define GRP_NOLD(P) do {                                                      \
    STEP_NOLD(P##0, 0); STEP_NOLD(P##1, 768); STEP_NOLD(P##2, 1536);          \
    obase += 576;                                                             \
    STEP_NOLD(P##3, 0); STEP_NOLD(P##4, 768); STEP_NOLD(P##5, 1536);          \
    obase += 576;                                                             \
    STEP_NOLD(P##6, 0); STEP_NOLD(P##7, 768); STEP_NOLD(P##8, 1536);          \
    obase += 576;                                                             \
} while (0)

// prologue batched loads (one group)
#define PF3B(Pa, Pb, Pc) do {                                                 \
    PF1S(Pa, 0); PF1S(Pb, 768); PF1S(Pc, 1536); lbase += 576;                 \
} while (0)
#define PF9B(P) do { PF3B(P##0,P##1,P##2); PF3B(P##3,P##4,P##5);              \
    PF3B(P##6,P##7,P##8); } while (0)

__global__ __launch_bounds__(64, 1) void scan_kernel(
    const float* __restrict__ x,
    const float* __restrict__ w,
    const float* __restrict__ bias,
    float* __restrict__ out)
{
    const int lane = threadIdx.x;
    const int g  = lane >> 2;                    // chain within wave (0..15)
    const int pr = lane & 3;
    const int p  = pr < 3 ? pr : 2;              // channel; lane3 mirrors ch2

    // XCD-pair swizzle (R10, verified: FETCH 96->48 MB): both halves of each
    // 128B line land on blocks with equal (blockIdx mod 8) -> same XCD L2.
    const int B = blockIdx.x;
    const int xs = B & 7, h = (B >> 3) & 1, j = B >> 4;
    const int i = j * 8 + xs;                    // 0..255
    const int b = i >> 1;                        // 0..127
    const int fq = ((i & 1) << 1) | h;           // 0..3 (16-f quarter)
    const int f = (fq << 4) + g;

    const int p1i = (p + 1) == 3 ? 0 : p + 1;
    const int p2i = (p + 2) >= 3 ? p - 1 : p + 2;
    float wA = w[p * 3 + p];
    float wB = w[p * 3 + p1i];
    float wC = w[p * 3 + p2i];
    float q  = bias[p];

    // constants in VGPRs (VOP3 forbids literals; 0/1.0 stay inline)
    float cPPW = PPWc, cNL2E = NL2Ef;
    float cB1 = B1f, cB2 = B2f, cB3 = B3f, cB4 = B4f, cB5 = B5f;

    // per-lane constant byte offset (channel row + f); bases are uniform SGPRs
    const int voff = p * 256 + f * 4;
    const float* lbase = x   + (size_t)b * (SEQ * FDIM) + 3 * FDIM;  // row 3
    float*       obase = out + (size_t)b * (SEQ * FDIM) + 3 * FDIM;  // row 3
    const float* hbase = x   + (size_t)b * (SEQ * FDIM);             // row 0
    float*       ohead = out + (size_t)b * (SEQ * FDIM);

    // head: plain load of s0, touch so compiler's waitcnt lands before any
    // asm loads are outstanding; asm store of the head copy.
    float s = *(const float*)((const char*)hbase + voff);
    asm volatile("" : "+v"(s), "+v"(wA), "+v"(wB), "+v"(wC), "+v"(q),
                      "+v"(cPPW), "+v"(cNL2E), "+v"(cB1), "+v"(cB2),
                      "+v"(cB3), "+v"(cB4), "+v"(cB5));
    asm volatile("global_store_dword %0, %1, %2"
                 :: "v"(voff), "v"(s), "s"(ohead) : "memory");

    float a_, d1_, d2_, u2_, dd_, m_, r_, e_, rl_;
    float c01_, c23_, rr_, r4_, pp_, zr_, z_, rlu_;

    DECL9(LA); DECL9(LB); DECL9(LC); DECL9(LD);  // quad buffer

    PF9B(LA);                                    // g0
    PF9B(LB);                                    // g1
    PF9B(LC);                                    // g2
    // outstanding: hst(1)+27 -> vmcnt(18) retires hst+LA; LB,LC in flight
    WAITVM(18, LA);

    // 27 iters x 4 groups: g0..g107. During group g issue loads for g+3 into
    // the buffer consumed 3 phases earlier (dead). Boundary wait vmcnt(27):
    // newest 27 = current phase's 18 + prior phase's 9 -> only requires
    // VMEM >= 2 phases (~2600 cy) old to have retired (loads AND stores).
    #pragma unroll 1
    for (int t = 0; t < 27; ++t) {
        GRP_LD(LA, LD);   WAITVM(27, LB);        // g=4t   ; ld g+3 -> D
        GRP_LD(LB, LA);   WAITVM(27, LC);        // g=4t+1 ; ld g+4 -> A
        GRP_LD(LC, LB);   WAITVM(27, LD);        // g=4t+2 ; ld g+5 -> B
        GRP_LD(LD, LC);   WAITVM(27, LA);        // g=4t+3 ; ld g+6 -> C
    }

    // epilogue: g108 (LA), g109 (LB), g110 (LC); no more loads
    GRP_NOLD(LA);         WAITVM(9, LB);         // newest 9 = st(g108)
    GRP_NOLD(LB);         WAITVM(9, LC);         // newest 9 = st(g109)
    GRP_NOLD(LC);                                // g110
}

extern "C" void kernel_launch(void* const* d_in, const int* in_sizes, int n_in,
                              void* d_out, int out_size, void* d_ws, size_t ws_size,
                              hipStream_t stream) {
    const float* x    = (const float*)d_in[0];
    const float* w    = (const float*)d_in[1];
    const float* bias = (const float*)d_in[2];
    float* out        = (float*)d_out;

    hipLaunchKernelGGL(scan_kernel, dim3(512), dim3(64), 0, stream,
                       x, w, bias, out);
}